// Round 2
// baseline (2865.587 us; speedup 1.0000x reference)
//
#include <hip/hip_runtime.h>
#include <math.h>

#define N_ATOMS 20000
#define M 12
#define B 41
#define ORIG 92
#define F 64
#define D 169        // 2F + B
#define DPAD 172     // D padded so LDS rows are 16B-aligned
#define NCONV 3
#define K 3
#define TWOK 6
#define H 128
#define N0 400
#define EPS 1e-5f
#define KD (K * D)   // 507
#define KB (K * B)   // 123

// ---------------- embedding: x = atom_fea @ emb_w + emb_b ----------------
__global__ void emb_kernel(const float* __restrict__ atom_fea,
                           const float* __restrict__ emb_w,
                           const float* __restrict__ emb_b,
                           float* __restrict__ x) {
    int i = blockIdx.x * blockDim.x + threadIdx.x;
    if (i >= N_ATOMS * F) return;
    int n = i / F, f = i % F;
    const float* a = atom_fea + n * ORIG;
    float acc = emb_b[f];
    #pragma unroll 4
    for (int d = 0; d < ORIG; ++d)
        acc = fmaf(a[d], emb_w[d * F + f], acc);
    x[i] = acc;
}

// ---------------- fused conv layer: one block per 2 atoms ----------------
// 256 threads = 2 halves of 128; half `a` handles atom n0+a.
// Within a half: threads 0..95  -> (k = tt/32, e0 = tt%32), own 4 columns
//                                  {e0, e0+32 (filter), e0+64, e0+96 (core)}
//                threads 96..126 -> 4 bond columns each (123 total)
//                thread 127      -> idle in matmul
// 4 cols x 12 rows accumulated in registers; filter/core softmax-sum fully
// in-thread; weights double-buffered with immediate-offset loads.

#define LOADW(W) do {                                              \
    _Pragma("unroll")                                              \
    for (int j_ = 0; j_ < 4; ++j_) {                               \
        _Pragma("unroll")                                          \
        for (int q_ = 0; q_ < 4; ++q_) W[q_][j_] = p[j_][q_ * D];  \
        p[j_] += 4 * D;                                            \
    }                                                              \
} while (0)

#define COMPUTE(W, dbase) do {                                                   \
    _Pragma("unroll")                                                            \
    for (int m_ = 0; m_ < M; ++m_) {                                             \
        float4 tv = *reinterpret_cast<const float4*>(tbase + m_ * DPAD + (dbase)); \
        _Pragma("unroll")                                                        \
        for (int j_ = 0; j_ < 4; ++j_) {                                         \
            acc[j_][m_] = fmaf(tv.x, W[0][j_], acc[j_][m_]);                     \
            acc[j_][m_] = fmaf(tv.y, W[1][j_], acc[j_][m_]);                     \
            acc[j_][m_] = fmaf(tv.z, W[2][j_], acc[j_][m_]);                     \
            acc[j_][m_] = fmaf(tv.w, W[3][j_], acc[j_][m_]);                     \
        }                                                                        \
    }                                                                            \
} while (0)

template <bool NEED_NBR>
__global__ __launch_bounds__(256, 4)
void conv_kernel(const float* __restrict__ xin,
                 const float* __restrict__ nbrin,
                 const int* __restrict__ idx,
                 const float* __restrict__ fc_w,   // (K,D,D)
                 const float* __restrict__ fc_b,   // (K,D)
                 const float* __restrict__ bn1_g,
                 const float* __restrict__ bn1_b,
                 const float* __restrict__ bn1_m,
                 const float* __restrict__ bn1_v,  // (K,D)
                 const float* __restrict__ bn2_g,
                 const float* __restrict__ bn2_b,
                 const float* __restrict__ bn2_m,
                 const float* __restrict__ bn2_v,  // (K,F)
                 const float* __restrict__ atom_w, // (K,2K)
                 const float* __restrict__ atom_b, // (2K)
                 const float* __restrict__ nbr_w,  // (K,2K)
                 const float* __restrict__ nbr_b,  // (2K)
                 float* __restrict__ xout,
                 float* __restrict__ nbrout) {
    __shared__ __align__(16) float s_total[2][M][DPAD];  // 16512 B
    __shared__ float s_nnk[2][K][M][B];                  // 11808 B
    __shared__ float s_sum[2][K][F];                     // 1536 B

    const int t = threadIdx.x;
    const int a = t >> 7;        // which atom half
    const int tt = t & 127;
    const int n0 = blockIdx.x * 2;

    // ---- stage total = [self(F) | gathered(F) | nbr(B)] for both atoms ----
    for (int i = t; i < 2 * M * D; i += 256) {
        int aa = i / (M * D);
        int r = i - aa * (M * D);
        int m = r / D, d = r - (r / D) * D;
        int n = n0 + aa;
        float v;
        if (d < F)            v = xin[n * F + d];
        else if (d < 2 * F)   v = xin[idx[n * M + m] * F + (d - F)];
        else                  v = nbrin[(n * M + m) * B + (d - 2 * F)];
        s_total[aa][m][d] = v;
    }
    __syncthreads();

    const float* tbase = &s_total[a][0][0];

    // ---- column assignment ----
    const bool type1 = (tt < 96);
    int kk[4] = {0, 0, 0, 0}, bb[4] = {0, 0, 0, 0};
    bool valid[4] = {false, false, false, false};
    const float* p[4];
    if (type1) {
        int k = tt >> 5, e0 = tt & 31;
        #pragma unroll
        for (int j = 0; j < 4; ++j) p[j] = fc_w + k * D * D + e0 + 32 * j;
    } else {
        int i0 = (tt - 96) << 2;
        #pragma unroll
        for (int j = 0; j < 4; ++j) {
            int c = i0 + j;
            valid[j] = (c < KB);
            int cc = valid[j] ? c : 0;
            kk[j] = cc / B;
            bb[j] = cc - kk[j] * B;
            p[j] = fc_w + kk[j] * D * D + 2 * F + bb[j];
        }
    }

    float acc[4][M];
    #pragma unroll
    for (int j = 0; j < 4; ++j)
        #pragma unroll
        for (int m = 0; m < M; ++m) acc[j][m] = 0.f;

    const bool do_mm = type1 || NEED_NBR;
    if (do_mm) {
        float wA[4][4], wB[4][4];
        LOADW(wA);                       // group 0
        for (int g = 0; g < 40; g += 2) {
            LOADW(wB);                   // group g+1
            COMPUTE(wA, g * 4);
            LOADW(wA);                   // group g+2
            COMPUTE(wB, g * 4 + 4);
        }
        LOADW(wB);                       // group 41
        COMPUTE(wA, 160);
        COMPUTE(wB, 164);
        {   // remainder d = 168
            float w1[4];
            #pragma unroll
            for (int j = 0; j < 4; ++j) w1[j] = p[j][0];
            #pragma unroll
            for (int m = 0; m < M; ++m) {
                float tv = tbase[m * DPAD + 168];
                #pragma unroll
                for (int j = 0; j < 4; ++j)
                    acc[j][m] = fmaf(tv, w1[j], acc[j][m]);
            }
        }
    }

    // ---- epilogue part 1: bn1 + route ----
    if (type1) {
        const int k = tt >> 5, e0 = tt & 31;
        #pragma unroll
        for (int pr = 0; pr < 2; ++pr) {
            const int e = e0 + 32 * pr;
            const int cf = k * D + e;        // filter column
            const int cr = k * D + F + e;    // core column
            float sc_f = bn1_g[cf] * rsqrtf(bn1_v[cf] + EPS);
            float sh_f = bn1_b[cf] - bn1_m[cf] * sc_f;
            float bi_f = fc_b[cf];
            float sc_c = bn1_g[cr] * rsqrtf(bn1_v[cr] + EPS);
            float sh_c = bn1_b[cr] - bn1_m[cr] * sc_c;
            float bi_c = fc_b[cr];
            float fv[M];
            float mx = -1e30f;
            #pragma unroll
            for (int m = 0; m < M; ++m) {
                fv[m] = fmaf(acc[pr][m] + bi_f, sc_f, sh_f);
                mx = fmaxf(mx, fv[m]);
            }
            float s = 0.f;
            #pragma unroll
            for (int m = 0; m < M; ++m) { fv[m] = expf(fv[m] - mx); s += fv[m]; }
            float inv = 1.f / s;
            float acc_s = 0.f;
            #pragma unroll
            for (int m = 0; m < M; ++m) {
                float rv = fmaf(acc[pr + 2][m] + bi_c, sc_c, sh_c);
                rv = fmaxf(rv, 0.f);
                acc_s = fmaf(fv[m] * inv, rv, acc_s);
            }
            const int c2 = k * F + e;
            float sc2 = bn2_g[c2] * rsqrtf(bn2_v[c2] + EPS);
            float sh2 = bn2_b[c2] - bn2_m[c2] * sc2;
            s_sum[a][k][e] = s_total[a][0][e] + fmaf(acc_s, sc2, sh2);
        }
    } else if (NEED_NBR) {
        #pragma unroll
        for (int j = 0; j < 4; ++j) {
            if (valid[j]) {
                const int col = kk[j] * D + 2 * F + bb[j];
                float sc = bn1_g[col] * rsqrtf(bn1_v[col] + EPS);
                float sh = bn1_b[col] - bn1_m[col] * sc;
                float bi = fc_b[col];
                #pragma unroll
                for (int m = 0; m < M; ++m)
                    s_nnk[a][kk[j]][m][bb[j]] =
                        fmaf(acc[j][m] + bi, sc, sh) + s_total[a][m][2 * F + bb[j]];
            }
        }
    }
    __syncthreads();

    // ---- atom gate: og = outk @ atom_w + atom_b, gate-softmax over k ----
    if (t < 2 * F) {
        int a2 = t >> 6, f = t & 63;
        float og[TWOK];
        #pragma unroll
        for (int j = 0; j < TWOK; ++j) {
            float v = atom_b[j];
            #pragma unroll
            for (int q = 0; q < K; ++q)
                v = fmaf(s_sum[a2][q][f], atom_w[q * TWOK + j], v);
            og[j] = v;
        }
        float mx = fmaxf(fmaxf(og[K], og[K + 1]), og[K + 2]);
        float e0 = expf(og[K] - mx), e1 = expf(og[K + 1] - mx), e2 = expf(og[K + 2] - mx);
        float inv = 1.f / (e0 + e1 + e2);
        xout[(n0 + a2) * F + f] = (og[0] * e0 + og[1] * e1 + og[2] * e2) * inv;
    }

    // ---- bond gate ----
    if (NEED_NBR) {
        for (int i = t; i < 2 * M * B; i += 256) {
            int a2 = i / (M * B);
            int r = i - a2 * (M * B);
            int m = r / B, b = r - m * B;
            float ng[TWOK];
            #pragma unroll
            for (int j = 0; j < TWOK; ++j) {
                float v = nbr_b[j];
                #pragma unroll
                for (int q = 0; q < K; ++q)
                    v = fmaf(s_nnk[a2][q][m][b], nbr_w[q * TWOK + j], v);
                ng[j] = v;
            }
            float mx = fmaxf(fmaxf(ng[K], ng[K + 1]), ng[K + 2]);
            float e0 = expf(ng[K] - mx), e1 = expf(ng[K + 1] - mx), e2 = expf(ng[K + 2] - mx);
            float inv = 1.f / (e0 + e1 + e2);
            nbrout[((n0 + a2) * M + m) * B + b] =
                (ng[0] * e0 + ng[1] * e1 + ng[2] * e2) * inv;
        }
    }
}

// ---------------- pooling: segment sums via atomics ----------------
__global__ void pool_kernel(const float* __restrict__ x,
                            const int* __restrict__ cidx,
                            float* __restrict__ sums,
                            float* __restrict__ cnt) {
    int i = blockIdx.x * blockDim.x + threadIdx.x;
    if (i >= N_ATOMS * F) return;
    int n = i / F, f = i % F;
    int c = cidx[n];
    atomicAdd(&sums[c * F + f], x[i]);
    if (f == 0) atomicAdd(&cnt[c], 1.0f);
}

// ---------------- head: mean -> relu -> fc1 -> relu -> out ----------------
__global__ void head_kernel(const float* __restrict__ sums,
                            const float* __restrict__ cnt,
                            const float* __restrict__ fc1_w,
                            const float* __restrict__ fc1_b,
                            const float* __restrict__ out_w,
                            const float* __restrict__ out_b,
                            float* __restrict__ out) {
    const int c = blockIdx.x;
    const int t = threadIdx.x;  // 128 threads
    __shared__ float a[F];
    __shared__ float red[H];
    float inv_cnt = 1.f / fmaxf(cnt[c], 1.0f);
    if (t < F) a[t] = fmaxf(sums[c * F + t] * inv_cnt, 0.f);
    __syncthreads();
    float hv = fc1_b[t];
    #pragma unroll 4
    for (int f = 0; f < F; ++f)
        hv = fmaf(a[f], fc1_w[f * H + t], hv);
    hv = fmaxf(hv, 0.f);
    red[t] = hv * out_w[t];
    __syncthreads();
    for (int s = H / 2; s > 0; s >>= 1) {
        if (t < s) red[t] += red[t + s];
        __syncthreads();
    }
    if (t == 0) out[c] = red[0] + out_b[0];
}

extern "C" void kernel_launch(void* const* d_in, const int* in_sizes, int n_in,
                              void* d_out, int out_size, void* d_ws, size_t ws_size,
                              hipStream_t stream) {
    (void)in_sizes; (void)n_in; (void)out_size; (void)ws_size;
    const float* atom_fea = (const float*)d_in[0];
    const float* nbr_fea  = (const float*)d_in[1];
    const int*   nbr_idx  = (const int*)d_in[2];
    const int*   cidx     = (const int*)d_in[3];
    // d_in[4] = n_crystals (fixed 400)
    const float* emb_w = (const float*)d_in[5];
    const float* emb_b = (const float*)d_in[6];
    const float* fc_w  = (const float*)d_in[7];
    const float* fc_b  = (const float*)d_in[8];
    const float* bn1_g = (const float*)d_in[9];
    const float* bn1_b = (const float*)d_in[10];
    const float* bn1_m = (const float*)d_in[11];
    const float* bn1_v = (const float*)d_in[12];
    const float* bn2_g = (const float*)d_in[13];
    const float* bn2_b = (const float*)d_in[14];
    const float* bn2_m = (const float*)d_in[15];
    const float* bn2_v = (const float*)d_in[16];
    const float* atom_w = (const float*)d_in[17];
    const float* atom_b = (const float*)d_in[18];
    const float* nbr_w  = (const float*)d_in[19];
    const float* nbr_b  = (const float*)d_in[20];
    const float* fc1_w  = (const float*)d_in[21];
    const float* fc1_b  = (const float*)d_in[22];
    const float* out_w  = (const float*)d_in[23];
    const float* out_b  = (const float*)d_in[24];
    float* out = (float*)d_out;

    float* xA   = (float*)d_ws;                    // N*F
    float* xB   = xA + (size_t)N_ATOMS * F;        // N*F
    float* nbrA = xB + (size_t)N_ATOMS * F;        // N*M*B
    float* nbrB = nbrA + (size_t)N_ATOMS * M * B;  // N*M*B
    float* sums = nbrB + (size_t)N_ATOMS * M * B;  // N0*F
    float* cnt  = sums + (size_t)N0 * F;           // N0

    emb_kernel<<<(N_ATOMS * F + 255) / 256, 256, 0, stream>>>(atom_fea, emb_w, emb_b, xA);

    const int grid = N_ATOMS / 2;  // 10000

    // conv 0: xA -> xB, nbr_fea -> nbrA
    conv_kernel<true><<<grid, 256, 0, stream>>>(
        xA, nbr_fea, nbr_idx,
        fc_w, fc_b, bn1_g, bn1_b, bn1_m, bn1_v,
        bn2_g, bn2_b, bn2_m, bn2_v,
        atom_w, atom_b, nbr_w, nbr_b, xB, nbrA);
    // conv 1: xB -> xA, nbrA -> nbrB
    conv_kernel<true><<<grid, 256, 0, stream>>>(
        xB, nbrA, nbr_idx,
        fc_w + (size_t)1 * K * D * D, fc_b + (size_t)1 * K * D,
        bn1_g + (size_t)1 * K * D, bn1_b + (size_t)1 * K * D,
        bn1_m + (size_t)1 * K * D, bn1_v + (size_t)1 * K * D,
        bn2_g + (size_t)1 * K * F, bn2_b + (size_t)1 * K * F,
        bn2_m + (size_t)1 * K * F, bn2_v + (size_t)1 * K * F,
        atom_w + (size_t)1 * K * TWOK, atom_b + (size_t)1 * TWOK,
        nbr_w + (size_t)1 * K * TWOK, nbr_b + (size_t)1 * TWOK, xA, nbrB);
    // conv 2 (last): xA -> xB; new_nbr is dead -> skip bond work
    conv_kernel<false><<<grid, 256, 0, stream>>>(
        xA, nbrB, nbr_idx,
        fc_w + (size_t)2 * K * D * D, fc_b + (size_t)2 * K * D,
        bn1_g + (size_t)2 * K * D, bn1_b + (size_t)2 * K * D,
        bn1_m + (size_t)2 * K * D, bn1_v + (size_t)2 * K * D,
        bn2_g + (size_t)2 * K * F, bn2_b + (size_t)2 * K * F,
        bn2_m + (size_t)2 * K * F, bn2_v + (size_t)2 * K * F,
        atom_w + (size_t)2 * K * TWOK, atom_b + (size_t)2 * TWOK,
        nbr_w + (size_t)2 * K * TWOK, nbr_b + (size_t)2 * TWOK, xB, nbrA);

    hipMemsetAsync(sums, 0, (size_t)(N0 * F + N0) * sizeof(float), stream);
    pool_kernel<<<(N_ATOMS * F + 255) / 256, 256, 0, stream>>>(xB, cidx, sums, cnt);
    head_kernel<<<N0, H, 0, stream>>>(sums, cnt, fc1_w, fc1_b, out_w, out_b, out);
}

// Round 3
// 1397.432 us; speedup vs baseline: 2.0506x; 2.0506x over previous
//
#include <hip/hip_runtime.h>
#include <math.h>

#define N_ATOMS 20000
#define M 12
#define B 41
#define ORIG 92
#define F 64
#define D 169        // 2F + B
#define DPAD 172     // D padded to multiple of 4 (zero-filled)
#define NCONV 3
#define K 3
#define TWOK 6
#define H 128
#define N0 400
#define EPS 1e-5f
#define KD (K * D)   // 507
#define KB (K * B)   // 123
#define WBLK (DPAD * 128)        // 22016 floats per weight block
#define WTSZ (NCONV * 4 * WBLK)  // 264192 floats total

// ---------------- embedding: x = atom_fea @ emb_w + emb_b ----------------
__global__ void emb_kernel(const float* __restrict__ atom_fea,
                           const float* __restrict__ emb_w,
                           const float* __restrict__ emb_b,
                           float* __restrict__ x) {
    int i = blockIdx.x * blockDim.x + threadIdx.x;
    if (i >= N_ATOMS * F) return;
    int n = i / F, f = i % F;
    const float* a = atom_fea + n * ORIG;
    float acc = emb_b[f];
    #pragma unroll 4
    for (int d = 0; d < ORIG; ++d)
        acc = fmaf(a[d], emb_w[d * F + f], acc);
    x[i] = acc;
}

// ---------------- weight transpose/pad: fc_w (NC,K,D,D) -> wt blocks ------
// wt layout per layer: 4 blocks of [DPAD][128]:
//   blk k<3 (gate): [dd][e0*4+j] = fc_w[l][k][dd][e0+32*j]   (e0<32, j<4)
//   blk 3 (bond)  : [dd][c]      = fc_w[l][c/41][dd][128+c%41]  (c<123)
// zero-padded for dd>=169 and invalid c.
__global__ void prep_kernel(const float* __restrict__ fc_w,
                            float* __restrict__ wt) {
    int i = blockIdx.x * blockDim.x + threadIdx.x;
    if (i >= WTSZ) return;
    int l   = i / (4 * WBLK);
    int r   = i % (4 * WBLK);
    int blk = r / WBLK;
    int r2  = r % WBLK;
    int dd  = r2 / 128;
    int c   = r2 % 128;
    float v = 0.f;
    if (dd < D) {
        if (blk < 3) {
            int e = (c >> 2) + 32 * (c & 3);   // e in [0,128)
            v = fc_w[((size_t)(l * K + blk) * D + dd) * D + e];
        } else if (c < KB) {
            int kk = c / B, bb = c - (c / B) * B;
            v = fc_w[((size_t)(l * K + kk) * D + dd) * D + 2 * F + bb];
        }
    }
    wt[i] = v;
}

// ---------------- fused conv layer: one block per 2 atoms ----------------
// 256 threads = 2 halves of 128; half `a` handles atom n0+a.
// Within a half: tt in [0,96): gate cols {e0+32j, j<4}, k = tt/32, e0 = tt%32
//                tt in [96,128): bond cols {i0+j}, i0 = (tt-96)*4
// Matmul is a single uniform code path (same stride 128) for all threads.
// Self features (d<64) are row-independent: computed once, init all 12 acc.

#define ACC1(A, WC) do {                  \
    A = fmaf(tv.x, w0.WC, A);             \
    A = fmaf(tv.y, w1.WC, A);             \
    A = fmaf(tv.z, w2.WC, A);             \
    A = fmaf(tv.w, w3.WC, A);             \
} while (0)

template <bool NEED_NBR>
__global__ __launch_bounds__(256, 2)
void conv_kernel(const float* __restrict__ xin,
                 const float* __restrict__ nbrin,
                 const int* __restrict__ idx,
                 const float* __restrict__ wt,     // this layer's 4*WBLK
                 const float* __restrict__ fc_b,   // (K,D)
                 const float* __restrict__ bn1_g,
                 const float* __restrict__ bn1_b,
                 const float* __restrict__ bn1_m,
                 const float* __restrict__ bn1_v,  // (K,D)
                 const float* __restrict__ bn2_g,
                 const float* __restrict__ bn2_b,
                 const float* __restrict__ bn2_m,
                 const float* __restrict__ bn2_v,  // (K,F)
                 const float* __restrict__ atom_w, // (K,2K)
                 const float* __restrict__ atom_b, // (2K)
                 const float* __restrict__ nbr_w,  // (K,2K)
                 const float* __restrict__ nbr_b,  // (2K)
                 float* __restrict__ xout,
                 float* __restrict__ nbrout) {
    __shared__ __align__(16) float s_total[2][M][DPAD];  // 16512 B
    __shared__ float s_nnk[2][K][M][B];                  // 11808 B
    __shared__ float s_sum[2][K][F];                     // 1536 B

    const int t = threadIdx.x;
    const int a = t >> 7;        // which atom half
    const int tt = t & 127;
    const int n0 = blockIdx.x * 2;

    // ---- stage total = [self(F) | gathered(F) | nbr(B)] for both atoms ----
    for (int i = t; i < 2 * M * D; i += 256) {
        int aa = i / (M * D);
        int r = i - aa * (M * D);
        int m = r / D, d = r - (r / D) * D;
        int n = n0 + aa;
        float v;
        if (d < F)            v = xin[n * F + d];
        else if (d < 2 * F)   v = xin[idx[n * M + m] * F + (d - F)];
        else                  v = nbrin[(n * M + m) * B + (d - 2 * F)];
        s_total[aa][m][d] = v;
    }
    if (t < 2 * M * 3) {  // zero the pad d = 169..171
        int aa = t / (M * 3);
        int r = t - aa * (M * 3);
        s_total[aa][r / 3][D + (r - (r / 3) * 3)] = 0.f;
    }
    __syncthreads();

    const float* tbase = &s_total[a][0][0];
    const bool type1 = (tt < 96);
    const int i0 = (tt - 96) << 2;
    const float* wp = type1 ? (wt + (tt >> 5) * WBLK + (tt & 31) * 4)
                            : (wt + 3 * WBLK + i0);

    // ---- self part: dd in [0,64), shared by all 12 rows ----
    float sacc[4] = {0.f, 0.f, 0.f, 0.f};
    for (int g = 0; g < 16; ++g) {
        float4 w0 = *reinterpret_cast<const float4*>(wp);
        float4 w1 = *reinterpret_cast<const float4*>(wp + 128);
        float4 w2 = *reinterpret_cast<const float4*>(wp + 256);
        float4 w3 = *reinterpret_cast<const float4*>(wp + 384);
        float4 tv = *reinterpret_cast<const float4*>(tbase + g * 4);
        ACC1(sacc[0], x);
        ACC1(sacc[1], y);
        ACC1(sacc[2], z);
        ACC1(sacc[3], w);
        wp += 512;
    }

    float acc[4][M];
    #pragma unroll
    for (int j = 0; j < 4; ++j)
        #pragma unroll
        for (int m = 0; m < M; ++m) acc[j][m] = sacc[j];

    // ---- per-row part: dd in [64,172) ----
    for (int g = 0; g < 27; ++g) {
        float4 w0 = *reinterpret_cast<const float4*>(wp);
        float4 w1 = *reinterpret_cast<const float4*>(wp + 128);
        float4 w2 = *reinterpret_cast<const float4*>(wp + 256);
        float4 w3 = *reinterpret_cast<const float4*>(wp + 384);
        const int dbase = 64 + g * 4;
        #pragma unroll
        for (int m = 0; m < M; ++m) {
            float4 tv = *reinterpret_cast<const float4*>(tbase + m * DPAD + dbase);
            ACC1(acc[0][m], x);
            ACC1(acc[1][m], y);
            ACC1(acc[2][m], z);
            ACC1(acc[3][m], w);
        }
        wp += 512;
    }

    // ---- epilogue part 1: bn1 + route ----
    if (type1) {
        const int k = tt >> 5, e0 = tt & 31;
        #pragma unroll
        for (int pr = 0; pr < 2; ++pr) {
            const int e = e0 + 32 * pr;
            const int cf = k * D + e;        // filter column (acc[pr])
            const int cr = k * D + F + e;    // core column   (acc[pr+2])
            float sc_f = bn1_g[cf] * rsqrtf(bn1_v[cf] + EPS);
            float sh_f = bn1_b[cf] - bn1_m[cf] * sc_f;
            float bi_f = fc_b[cf];
            float sc_c = bn1_g[cr] * rsqrtf(bn1_v[cr] + EPS);
            float sh_c = bn1_b[cr] - bn1_m[cr] * sc_c;
            float bi_c = fc_b[cr];
            float fv[M];
            float mx = -1e30f;
            #pragma unroll
            for (int m = 0; m < M; ++m) {
                fv[m] = fmaf(acc[pr][m] + bi_f, sc_f, sh_f);
                mx = fmaxf(mx, fv[m]);
            }
            float s = 0.f;
            #pragma unroll
            for (int m = 0; m < M; ++m) { fv[m] = expf(fv[m] - mx); s += fv[m]; }
            float inv = 1.f / s;
            float acc_s = 0.f;
            #pragma unroll
            for (int m = 0; m < M; ++m) {
                float rv = fmaf(acc[pr + 2][m] + bi_c, sc_c, sh_c);
                rv = fmaxf(rv, 0.f);
                acc_s = fmaf(fv[m] * inv, rv, acc_s);
            }
            const int c2 = k * F + e;
            float sc2 = bn2_g[c2] * rsqrtf(bn2_v[c2] + EPS);
            float sh2 = bn2_b[c2] - bn2_m[c2] * sc2;
            s_sum[a][k][e] = s_total[a][0][e] + fmaf(acc_s, sc2, sh2);
        }
    } else if (NEED_NBR) {
        #pragma unroll
        for (int j = 0; j < 4; ++j) {
            int c = i0 + j;
            if (c < KB) {
                int kk = c / B, bb = c - (c / B) * B;
                const int col = kk * D + 2 * F + bb;
                float sc = bn1_g[col] * rsqrtf(bn1_v[col] + EPS);
                float sh = bn1_b[col] - bn1_m[col] * sc;
                float bi = fc_b[col];
                #pragma unroll
                for (int m = 0; m < M; ++m)
                    s_nnk[a][kk][m][bb] =
                        fmaf(acc[j][m] + bi, sc, sh) + s_total[a][m][2 * F + bb];
            }
        }
    }
    __syncthreads();

    // ---- atom gate ----
    if (t < 2 * F) {
        int a2 = t >> 6, f = t & 63;
        float og[TWOK];
        #pragma unroll
        for (int j = 0; j < TWOK; ++j) {
            float v = atom_b[j];
            #pragma unroll
            for (int q = 0; q < K; ++q)
                v = fmaf(s_sum[a2][q][f], atom_w[q * TWOK + j], v);
            og[j] = v;
        }
        float mx = fmaxf(fmaxf(og[K], og[K + 1]), og[K + 2]);
        float e0 = expf(og[K] - mx), e1 = expf(og[K + 1] - mx), e2 = expf(og[K + 2] - mx);
        float inv = 1.f / (e0 + e1 + e2);
        xout[(n0 + a2) * F + f] = (og[0] * e0 + og[1] * e1 + og[2] * e2) * inv;
    }

    // ---- bond gate ----
    if (NEED_NBR) {
        for (int i = t; i < 2 * M * B; i += 256) {
            int a2 = i / (M * B);
            int r = i - a2 * (M * B);
            int m = r / B, b = r - m * B;
            float ng[TWOK];
            #pragma unroll
            for (int j = 0; j < TWOK; ++j) {
                float v = nbr_b[j];
                #pragma unroll
                for (int q = 0; q < K; ++q)
                    v = fmaf(s_nnk[a2][q][m][b], nbr_w[q * TWOK + j], v);
                ng[j] = v;
            }
            float mx = fmaxf(fmaxf(ng[K], ng[K + 1]), ng[K + 2]);
            float e0 = expf(ng[K] - mx), e1 = expf(ng[K + 1] - mx), e2 = expf(ng[K + 2] - mx);
            float inv = 1.f / (e0 + e1 + e2);
            nbrout[((n0 + a2) * M + m) * B + b] =
                (ng[0] * e0 + ng[1] * e1 + ng[2] * e2) * inv;
        }
    }
}

// ---------------- pooling: segment sums via atomics ----------------
__global__ void pool_kernel(const float* __restrict__ x,
                            const int* __restrict__ cidx,
                            float* __restrict__ sums,
                            float* __restrict__ cnt) {
    int i = blockIdx.x * blockDim.x + threadIdx.x;
    if (i >= N_ATOMS * F) return;
    int n = i / F, f = i % F;
    int c = cidx[n];
    atomicAdd(&sums[c * F + f], x[i]);
    if (f == 0) atomicAdd(&cnt[c], 1.0f);
}

// ---------------- head: mean -> relu -> fc1 -> relu -> out ----------------
__global__ void head_kernel(const float* __restrict__ sums,
                            const float* __restrict__ cnt,
                            const float* __restrict__ fc1_w,
                            const float* __restrict__ fc1_b,
                            const float* __restrict__ out_w,
                            const float* __restrict__ out_b,
                            float* __restrict__ out) {
    const int c = blockIdx.x;
    const int t = threadIdx.x;  // 128 threads
    __shared__ float a[F];
    __shared__ float red[H];
    float inv_cnt = 1.f / fmaxf(cnt[c], 1.0f);
    if (t < F) a[t] = fmaxf(sums[c * F + t] * inv_cnt, 0.f);
    __syncthreads();
    float hv = fc1_b[t];
    #pragma unroll 4
    for (int f = 0; f < F; ++f)
        hv = fmaf(a[f], fc1_w[f * H + t], hv);
    hv = fmaxf(hv, 0.f);
    red[t] = hv * out_w[t];
    __syncthreads();
    for (int s = H / 2; s > 0; s >>= 1) {
        if (t < s) red[t] += red[t + s];
        __syncthreads();
    }
    if (t == 0) out[c] = red[0] + out_b[0];
}

extern "C" void kernel_launch(void* const* d_in, const int* in_sizes, int n_in,
                              void* d_out, int out_size, void* d_ws, size_t ws_size,
                              hipStream_t stream) {
    (void)in_sizes; (void)n_in; (void)out_size; (void)ws_size;
    const float* atom_fea = (const float*)d_in[0];
    const float* nbr_fea  = (const float*)d_in[1];
    const int*   nbr_idx  = (const int*)d_in[2];
    const int*   cidx     = (const int*)d_in[3];
    // d_in[4] = n_crystals (fixed 400)
    const float* emb_w = (const float*)d_in[5];
    const float* emb_b = (const float*)d_in[6];
    const float* fc_w  = (const float*)d_in[7];
    const float* fc_b  = (const float*)d_in[8];
    const float* bn1_g = (const float*)d_in[9];
    const float* bn1_b = (const float*)d_in[10];
    const float* bn1_m = (const float*)d_in[11];
    const float* bn1_v = (const float*)d_in[12];
    const float* bn2_g = (const float*)d_in[13];
    const float* bn2_b = (const float*)d_in[14];
    const float* bn2_m = (const float*)d_in[15];
    const float* bn2_v = (const float*)d_in[16];
    const float* atom_w = (const float*)d_in[17];
    const float* atom_b = (const float*)d_in[18];
    const float* nbr_w  = (const float*)d_in[19];
    const float* nbr_b  = (const float*)d_in[20];
    const float* fc1_w  = (const float*)d_in[21];
    const float* fc1_b  = (const float*)d_in[22];
    const float* out_w  = (const float*)d_in[23];
    const float* out_b  = (const float*)d_in[24];
    float* out = (float*)d_out;

    float* xA   = (float*)d_ws;                    // N*F
    float* xB   = xA + (size_t)N_ATOMS * F;        // N*F
    float* nbrA = xB + (size_t)N_ATOMS * F;        // N*M*B
    float* nbrB = nbrA + (size_t)N_ATOMS * M * B;  // N*M*B
    float* sums = nbrB + (size_t)N_ATOMS * M * B;  // N0*F
    float* cnt  = sums + (size_t)N0 * F;           // N0
    float* wt   = cnt + N0;                        // WTSZ

    prep_kernel<<<(WTSZ + 255) / 256, 256, 0, stream>>>(fc_w, wt);
    emb_kernel<<<(N_ATOMS * F + 255) / 256, 256, 0, stream>>>(atom_fea, emb_w, emb_b, xA);

    const int grid = N_ATOMS / 2;  // 10000

    // conv 0: xA -> xB, nbr_fea -> nbrA
    conv_kernel<true><<<grid, 256, 0, stream>>>(
        xA, nbr_fea, nbr_idx,
        wt, fc_b, bn1_g, bn1_b, bn1_m, bn1_v,
        bn2_g, bn2_b, bn2_m, bn2_v,
        atom_w, atom_b, nbr_w, nbr_b, xB, nbrA);
    // conv 1: xB -> xA, nbrA -> nbrB
    conv_kernel<true><<<grid, 256, 0, stream>>>(
        xB, nbrA, nbr_idx,
        wt + (size_t)1 * 4 * WBLK, fc_b + (size_t)1 * K * D,
        bn1_g + (size_t)1 * K * D, bn1_b + (size_t)1 * K * D,
        bn1_m + (size_t)1 * K * D, bn1_v + (size_t)1 * K * D,
        bn2_g + (size_t)1 * K * F, bn2_b + (size_t)1 * K * F,
        bn2_m + (size_t)1 * K * F, bn2_v + (size_t)1 * K * F,
        atom_w + (size_t)1 * K * TWOK, atom_b + (size_t)1 * TWOK,
        nbr_w + (size_t)1 * K * TWOK, nbr_b + (size_t)1 * TWOK, xA, nbrB);
    // conv 2 (last): xA -> xB; new_nbr is dead -> skip bond epilogue
    conv_kernel<false><<<grid, 256, 0, stream>>>(
        xA, nbrB, nbr_idx,
        wt + (size_t)2 * 4 * WBLK, fc_b + (size_t)2 * K * D,
        bn1_g + (size_t)2 * K * D, bn1_b + (size_t)2 * K * D,
        bn1_m + (size_t)2 * K * D, bn1_v + (size_t)2 * K * D,
        bn2_g + (size_t)2 * K * F, bn2_b + (size_t)2 * K * F,
        bn2_m + (size_t)2 * K * F, bn2_v + (size_t)2 * K * F,
        atom_w + (size_t)2 * K * TWOK, atom_b + (size_t)2 * TWOK,
        nbr_w + (size_t)2 * K * TWOK, nbr_b + (size_t)2 * TWOK, xB, nbrA);

    hipMemsetAsync(sums, 0, (size_t)(N0 * F + N0) * sizeof(float), stream);
    pool_kernel<<<(N_ATOMS * F + 255) / 256, 256, 0, stream>>>(xB, cidx, sums, cnt);
    head_kernel<<<N0, H, 0, stream>>>(sums, cnt, fc1_w, fc1_b, out_w, out_b, out);
}

// Round 4
// 1379.688 us; speedup vs baseline: 2.0770x; 1.0129x over previous
//
#include <hip/hip_runtime.h>
#include <math.h>

#define N_ATOMS 20000
#define M 12
#define B 41
#define ORIG 92
#define F 64
#define D 169        // 2F + B
#define NCONV 3
#define K 3
#define TWOK 6
#define H 128
#define N0 400
#define EPS 1e-5f
#define KB (K * B)   // 123

// MFMA geometry
#define KPAD 192                 // K dim padded to 6 steps of 32
#define NS 6                     // K-steps
#define ROWS 64                  // 4 atoms x 16 rows
#define ATOMS_PER_BLK 4
#define LFRAG 98304              // ushorts per (layer,img) fragment image: NS*32*64*8
#define WT_USHORTS (NCONV * 2 * LFRAG)

typedef __attribute__((ext_vector_type(8))) short bf16x8;
typedef __attribute__((ext_vector_type(4))) float f32x4;

// RNE f32 -> bf16 (bit trick), returns ushort pattern
__device__ inline unsigned short f32_to_bf16(float v) {
    unsigned int x = __float_as_uint(v);
    unsigned int r = (x + 0x7fffu + ((x >> 16) & 1u)) >> 16;
    return (unsigned short)r;
}
__device__ inline float bf16_to_f32(unsigned short u) {
    return __uint_as_float(((unsigned int)u) << 16);
}

// ---------------- embedding: x = atom_fea @ emb_w + emb_b ----------------
__global__ void emb_kernel(const float* __restrict__ atom_fea,
                           const float* __restrict__ emb_w,
                           const float* __restrict__ emb_b,
                           float* __restrict__ x) {
    int i = blockIdx.x * blockDim.x + threadIdx.x;
    if (i >= N_ATOMS * F) return;
    int n = i / F, f = i % F;
    const float* a = atom_fea + n * ORIG;
    float acc = emb_b[f];
    #pragma unroll 4
    for (int d = 0; d < ORIG; ++d)
        acc = fmaf(a[d], emb_w[d * F + f], acc);
    x[i] = acc;
}

// ------- prep: fc_w (NC,K,D,D) -> bf16 hi/lo B-fragment images ----------
// Padded col space (512): block b3 = col>>7:
//   b3<3 (gate k=b3): cc=col&127 -> source W col cc (filter 0-63, core 64-127)
//   b3==3 (bond): cc<123 -> k=cc/41, source col 128 + cc%41; else zero
// Fragment order: [layer][img][s][c16][lane][e] (ushort), where
//   col = c16*16 + (lane&15), k = s*32 + (lane>>4)*8 + e
__global__ void prep_kernel(const float* __restrict__ fc_w,
                            unsigned short* __restrict__ wt) {
    int i = blockIdx.x * blockDim.x + threadIdx.x;
    if (i >= NCONV * LFRAG) return;
    int layer = i / LFRAG;
    int r = i % LFRAG;
    int s = r / 16384;
    int r2 = r % 16384;
    int c16 = r2 / 512;
    int r3 = r2 % 512;
    int lane = r3 / 8;
    int e = r3 % 8;
    int col = c16 * 16 + (lane & 15);
    int k = s * 32 + (lane >> 4) * 8 + e;
    float v = 0.f;
    if (k < D) {
        int b3 = col >> 7, cc = col & 127;
        if (b3 < 3) {
            v = fc_w[((size_t)(layer * K + b3) * D + k) * D + cc];
        } else if (cc < KB) {
            int kk = cc / B, bb = cc - kk * B;
            v = fc_w[((size_t)(layer * K + kk) * D + k) * D + 2 * F + bb];
        }
    }
    unsigned short hi = f32_to_bf16(v);
    float hf = bf16_to_f32(hi);
    unsigned short lo = f32_to_bf16(v - hf);
    size_t off = (size_t)s * 16384 + c16 * 512 + lane * 8 + e;
    wt[(size_t)(layer * 2 + 0) * LFRAG + off] = hi;
    wt[(size_t)(layer * 2 + 1) * LFRAG + off] = lo;
}

// ---------------- MFMA conv: one block per 4 atoms ----------------
// A = [64 rows (4 atoms x 16, rows 12-15 pad=0)][192 k] bf16 hi/lo in LDS
//   (XOR swizzle: byte_in_row ^= (row&7)<<4)
// 4 waves; wave w owns col-tiles c16 = w*8 .. w*8+7 (128 cols).
//   w<3: gate block k=w (tiles 0-3 filter e, 4-7 core e)
//   w=3: bond block (cc = t*16+lane15; k=cc/41, b=cc%41, cc<123)
// C layout per 16x16 tile: col=lane&15, row=(lane>>4)*4+reg  [verified]
template <bool NEED_NBR>
__global__ __launch_bounds__(256, 2)
void conv_mfma(const float* __restrict__ xin,
               const float* __restrict__ nbrin,
               const int* __restrict__ idx,
               const unsigned short* __restrict__ wtl,  // this layer's frags
               const float* __restrict__ fc_b,   // (K,D)
               const float* __restrict__ bn1_g,
               const float* __restrict__ bn1_b,
               const float* __restrict__ bn1_m,
               const float* __restrict__ bn1_v,  // (K,D)
               const float* __restrict__ bn2_g,
               const float* __restrict__ bn2_b,
               const float* __restrict__ bn2_m,
               const float* __restrict__ bn2_v,  // (K,F)
               const float* __restrict__ atom_w, // (K,2K)
               const float* __restrict__ atom_b, // (2K)
               const float* __restrict__ nbr_w,  // (K,2K)
               const float* __restrict__ nbr_b,  // (2K)
               float* __restrict__ xout,
               float* __restrict__ nbrout) {
    __shared__ unsigned short s_a[2 * ROWS * KPAD];  // 49152 B (hi, lo images)
    __shared__ float s_sum[ATOMS_PER_BLK * K * F];   // 3072 B

    const int t = threadIdx.x;
    const int w = t >> 6;          // wave id
    const int l = t & 63;          // lane
    const int l15 = l & 15;
    const int lane3 = l >> 4;
    const int n0 = blockIdx.x * ATOMS_PER_BLK;

    // ---- stage A (bf16 hi/lo, swizzled) ----
    for (int i = t; i < ROWS * KPAD; i += 256) {
        int row = i / KPAD;
        int k = i - row * KPAD;
        int a = row >> 4, m = row & 15;
        int n = n0 + a;
        float v = 0.f;
        if (m < M) {
            if (k < F)            v = xin[n * F + k];
            else if (k < 2 * F)   v = xin[idx[n * M + m] * F + (k - F)];
            else if (k < D)       v = nbrin[(n * M + m) * B + (k - 2 * F)];
        }
        unsigned short hi = f32_to_bf16(v);
        unsigned short lo = f32_to_bf16(v - bf16_to_f32(hi));
        int byte = row * (KPAD * 2) + ((k * 2) ^ ((row & 7) << 4));
        s_a[byte >> 1] = hi;
        s_a[(byte >> 1) + ROWS * KPAD] = lo;
    }
    __syncthreads();

    // ---- MFMA main loop: 4 split passes accumulated ----
    f32x4 acc[4][8];
    #pragma unroll
    for (int a = 0; a < 4; ++a)
        #pragma unroll
        for (int tt = 0; tt < 8; ++tt)
            acc[a][tt] = (f32x4){0.f, 0.f, 0.f, 0.f};

    if (!(w == 3 && !NEED_NBR)) {
        for (int s = 0; s < NS; ++s) {
            bf16x8 ah[4], al[4];
            #pragma unroll
            for (int a = 0; a < 4; ++a) {
                int row = a * 16 + l15;
                int koff = s * 64 + lane3 * 16;                 // bytes
                int byte = row * (KPAD * 2) + (koff ^ ((row & 7) << 4));
                ah[a] = *reinterpret_cast<const bf16x8*>(&s_a[byte >> 1]);
                al[a] = *reinterpret_cast<const bf16x8*>(&s_a[(byte >> 1) + ROWS * KPAD]);
            }
            #pragma unroll
            for (int tt = 0; tt < 8; ++tt) {
                const unsigned short* wp =
                    wtl + (size_t)s * 16384 + (w * 8 + tt) * 512 + l * 8;
                bf16x8 bh = *reinterpret_cast<const bf16x8*>(wp);
                bf16x8 bl = *reinterpret_cast<const bf16x8*>(wp + LFRAG);
                #pragma unroll
                for (int a = 0; a < 4; ++a) {
                    acc[a][tt] = __builtin_amdgcn_mfma_f32_16x16x32_bf16(ah[a], bh, acc[a][tt], 0, 0, 0);
                    acc[a][tt] = __builtin_amdgcn_mfma_f32_16x16x32_bf16(ah[a], bl, acc[a][tt], 0, 0, 0);
                    acc[a][tt] = __builtin_amdgcn_mfma_f32_16x16x32_bf16(al[a], bh, acc[a][tt], 0, 0, 0);
                    acc[a][tt] = __builtin_amdgcn_mfma_f32_16x16x32_bf16(al[a], bl, acc[a][tt], 0, 0, 0);
                }
            }
        }
    }
    __syncthreads();   // all waves done reading s_a (bond wave will overlay it)

    float* s_nnk = reinterpret_cast<float*>(s_a);  // [4][3][12][41] f32 = 23.6 KB

    if (w < 3) {
        const int k = w;
        #pragma unroll
        for (int a = 0; a < 4; ++a) {
            #pragma unroll
            for (int tt = 0; tt < 4; ++tt) {
                int e = tt * 16 + l15;
                int cf = k * D + e, cr = cf + F, c2 = k * F + e;
                float sc_f = bn1_g[cf] * rsqrtf(bn1_v[cf] + EPS);
                float sh_f = bn1_b[cf] - bn1_m[cf] * sc_f;
                float bi_f = fc_b[cf];
                float sc_c = bn1_g[cr] * rsqrtf(bn1_v[cr] + EPS);
                float sh_c = bn1_b[cr] - bn1_m[cr] * sc_c;
                float bi_c = fc_b[cr];
                bool act = (lane3 < 3);   // rows 12-15 are pad
                float fv[4], cv[4];
                #pragma unroll
                for (int r = 0; r < 4; ++r) {
                    fv[r] = fmaf(acc[a][tt][r] + bi_f, sc_f, sh_f);
                    cv[r] = fmaxf(fmaf(acc[a][tt + 4][r] + bi_c, sc_c, sh_c), 0.f);
                }
                float mx = act ? fmaxf(fmaxf(fv[0], fv[1]), fmaxf(fv[2], fv[3])) : -1e30f;
                mx = fmaxf(mx, __shfl_xor(mx, 16));
                mx = fmaxf(mx, __shfl_xor(mx, 32));
                float se = 0.f, sp = 0.f;
                #pragma unroll
                for (int r = 0; r < 4; ++r) {
                    float ex = act ? expf(fv[r] - mx) : 0.f;
                    se += ex;
                    sp = fmaf(ex, cv[r], sp);
                }
                se += __shfl_xor(se, 16);
                se += __shfl_xor(se, 32);
                sp += __shfl_xor(sp, 16);
                sp += __shfl_xor(sp, 32);
                float summed = sp / se;
                float sc2 = bn2_g[c2] * rsqrtf(bn2_v[c2] + EPS);
                float sh2 = bn2_b[c2] - bn2_m[c2] * sc2;
                float outv = xin[(n0 + a) * F + e] + fmaf(summed, sc2, sh2);
                if (lane3 == 0) s_sum[(a * K + k) * F + e] = outv;
            }
        }
    } else if (NEED_NBR) {
        #pragma unroll
        for (int a = 0; a < 4; ++a) {
            #pragma unroll
            for (int tt = 0; tt < 8; ++tt) {
                int cc = tt * 16 + l15;
                if (cc < KB) {
                    int kk = cc / B, bb = cc - kk * B;
                    int col = kk * D + 2 * F + bb;
                    float sc = bn1_g[col] * rsqrtf(bn1_v[col] + EPS);
                    float sh = bn1_b[col] - bn1_m[col] * sc;
                    float bi = fc_b[col];
                    #pragma unroll
                    for (int r = 0; r < 4; ++r) {
                        int m = lane3 * 4 + r;
                        if (m < M) {
                            float v = fmaf(acc[a][tt][r] + bi, sc, sh)
                                    + nbrin[((n0 + a) * M + m) * B + bb];
                            s_nnk[((a * K + kk) * M + m) * B + bb] = v;
                        }
                    }
                }
            }
        }
    }
    __syncthreads();

    // ---- atom gate: 256 threads = 4 atoms x 64 f ----
    {
        int a2 = t >> 6, f = t & 63;
        float og[TWOK];
        #pragma unroll
        for (int j = 0; j < TWOK; ++j) {
            float v = atom_b[j];
            #pragma unroll
            for (int q = 0; q < K; ++q)
                v = fmaf(s_sum[(a2 * K + q) * F + f], atom_w[q * TWOK + j], v);
            og[j] = v;
        }
        float mx = fmaxf(fmaxf(og[K], og[K + 1]), og[K + 2]);
        float e0 = expf(og[K] - mx), e1 = expf(og[K + 1] - mx), e2 = expf(og[K + 2] - mx);
        float inv = 1.f / (e0 + e1 + e2);
        xout[(n0 + a2) * F + f] = (og[0] * e0 + og[1] * e1 + og[2] * e2) * inv;
    }

    // ---- bond gate ----
    if (NEED_NBR) {
        for (int i = t; i < ATOMS_PER_BLK * M * B; i += 256) {
            int a2 = i / (M * B);
            int r = i - a2 * (M * B);
            int m = r / B, b = r - m * B;
            float ng[TWOK];
            #pragma unroll
            for (int j = 0; j < TWOK; ++j) {
                float v = nbr_b[j];
                #pragma unroll
                for (int q = 0; q < K; ++q)
                    v = fmaf(s_nnk[((a2 * K + q) * M + m) * B + b], nbr_w[q * TWOK + j], v);
                ng[j] = v;
            }
            float mx = fmaxf(fmaxf(ng[K], ng[K + 1]), ng[K + 2]);
            float e0 = expf(ng[K] - mx), e1 = expf(ng[K + 1] - mx), e2 = expf(ng[K + 2] - mx);
            float inv = 1.f / (e0 + e1 + e2);
            nbrout[((n0 + a2) * M + m) * B + b] =
                (ng[0] * e0 + ng[1] * e1 + ng[2] * e2) * inv;
        }
    }
}

// ---------------- pooling: segment sums via atomics ----------------
__global__ void pool_kernel(const float* __restrict__ x,
                            const int* __restrict__ cidx,
                            float* __restrict__ sums,
                            float* __restrict__ cnt) {
    int i = blockIdx.x * blockDim.x + threadIdx.x;
    if (i >= N_ATOMS * F) return;
    int n = i / F, f = i % F;
    int c = cidx[n];
    atomicAdd(&sums[c * F + f], x[i]);
    if (f == 0) atomicAdd(&cnt[c], 1.0f);
}

// ---------------- head: mean -> relu -> fc1 -> relu -> out ----------------
__global__ void head_kernel(const float* __restrict__ sums,
                            const float* __restrict__ cnt,
                            const float* __restrict__ fc1_w,
                            const float* __restrict__ fc1_b,
                            const float* __restrict__ out_w,
                            const float* __restrict__ out_b,
                            float* __restrict__ out) {
    const int c = blockIdx.x;
    const int t = threadIdx.x;  // 128 threads
    __shared__ float a[F];
    __shared__ float red[H];
    float inv_cnt = 1.f / fmaxf(cnt[c], 1.0f);
    if (t < F) a[t] = fmaxf(sums[c * F + t] * inv_cnt, 0.f);
    __syncthreads();
    float hv = fc1_b[t];
    #pragma unroll 4
    for (int f = 0; f < F; ++f)
        hv = fmaf(a[f], fc1_w[f * H + t], hv);
    hv = fmaxf(hv, 0.f);
    red[t] = hv * out_w[t];
    __syncthreads();
    for (int s = H / 2; s > 0; s >>= 1) {
        if (t < s) red[t] += red[t + s];
        __syncthreads();
    }
    if (t == 0) out[c] = red[0] + out_b[0];
}

extern "C" void kernel_launch(void* const* d_in, const int* in_sizes, int n_in,
                              void* d_out, int out_size, void* d_ws, size_t ws_size,
                              hipStream_t stream) {
    (void)in_sizes; (void)n_in; (void)out_size; (void)ws_size;
    const float* atom_fea = (const float*)d_in[0];
    const float* nbr_fea  = (const float*)d_in[1];
    const int*   nbr_idx  = (const int*)d_in[2];
    const int*   cidx     = (const int*)d_in[3];
    // d_in[4] = n_crystals (fixed 400)
    const float* emb_w = (const float*)d_in[5];
    const float* emb_b = (const float*)d_in[6];
    const float* fc_w  = (const float*)d_in[7];
    const float* fc_b  = (const float*)d_in[8];
    const float* bn1_g = (const float*)d_in[9];
    const float* bn1_b = (const float*)d_in[10];
    const float* bn1_m = (const float*)d_in[11];
    const float* bn1_v = (const float*)d_in[12];
    const float* bn2_g = (const float*)d_in[13];
    const float* bn2_b = (const float*)d_in[14];
    const float* bn2_m = (const float*)d_in[15];
    const float* bn2_v = (const float*)d_in[16];
    const float* atom_w = (const float*)d_in[17];
    const float* atom_b = (const float*)d_in[18];
    const float* nbr_w  = (const float*)d_in[19];
    const float* nbr_b  = (const float*)d_in[20];
    const float* fc1_w  = (const float*)d_in[21];
    const float* fc1_b  = (const float*)d_in[22];
    const float* out_w  = (const float*)d_in[23];
    const float* out_b  = (const float*)d_in[24];
    float* out = (float*)d_out;

    float* xA   = (float*)d_ws;                    // N*F
    float* xB   = xA + (size_t)N_ATOMS * F;        // N*F
    float* nbrA = xB + (size_t)N_ATOMS * F;        // N*M*B
    float* nbrB = nbrA + (size_t)N_ATOMS * M * B;  // N*M*B
    float* sums = nbrB + (size_t)N_ATOMS * M * B;  // N0*F
    float* cnt  = sums + (size_t)N0 * F;           // N0
    unsigned short* wt = (unsigned short*)(cnt + N0);  // WT_USHORTS

    prep_kernel<<<(NCONV * LFRAG + 255) / 256, 256, 0, stream>>>(fc_w, wt);
    emb_kernel<<<(N_ATOMS * F + 255) / 256, 256, 0, stream>>>(atom_fea, emb_w, emb_b, xA);

    const int grid = N_ATOMS / ATOMS_PER_BLK;  // 5000

    // conv 0: xA -> xB, nbr_fea -> nbrA
    conv_mfma<true><<<grid, 256, 0, stream>>>(
        xA, nbr_fea, nbr_idx,
        wt, fc_b, bn1_g, bn1_b, bn1_m, bn1_v,
        bn2_g, bn2_b, bn2_m, bn2_v,
        atom_w, atom_b, nbr_w, nbr_b, xB, nbrA);
    // conv 1: xB -> xA, nbrA -> nbrB
    conv_mfma<true><<<grid, 256, 0, stream>>>(
        xB, nbrA, nbr_idx,
        wt + (size_t)2 * LFRAG, fc_b + (size_t)1 * K * D,
        bn1_g + (size_t)1 * K * D, bn1_b + (size_t)1 * K * D,
        bn1_m + (size_t)1 * K * D, bn1_v + (size_t)1 * K * D,
        bn2_g + (size_t)1 * K * F, bn2_b + (size_t)1 * K * F,
        bn2_m + (size_t)1 * K * F, bn2_v + (size_t)1 * K * F,
        atom_w + (size_t)1 * K * TWOK, atom_b + (size_t)1 * TWOK,
        nbr_w + (size_t)1 * K * TWOK, nbr_b + (size_t)1 * TWOK, xA, nbrB);
    // conv 2 (last): xA -> xB; new_nbr dead -> skip bond work entirely
    conv_mfma<false><<<grid, 256, 0, stream>>>(
        xA, nbrB, nbr_idx,
        wt + (size_t)4 * LFRAG, fc_b + (size_t)2 * K * D,
        bn1_g + (size_t)2 * K * D, bn1_b + (size_t)2 * K * D,
        bn1_m + (size_t)2 * K * D, bn1_v + (size_t)2 * K * D,
        bn2_g + (size_t)2 * K * F, bn2_b + (size_t)2 * K * F,
        bn2_m + (size_t)2 * K * F, bn2_v + (size_t)2 * K * F,
        atom_w + (size_t)2 * K * TWOK, atom_b + (size_t)2 * TWOK,
        nbr_w + (size_t)2 * K * TWOK, nbr_b + (size_t)2 * TWOK, xB, nbrA);

    hipMemsetAsync(sums, 0, (size_t)(N0 * F + N0) * sizeof(float), stream);
    pool_kernel<<<(N_ATOMS * F + 255) / 256, 256, 0, stream>>>(xB, cidx, sums, cnt);
    head_kernel<<<N0, H, 0, stream>>>(sums, cnt, fc1_w, fc1_b, out_w, out_b, out);
}

// Round 5
// 980.116 us; speedup vs baseline: 2.9237x; 1.4077x over previous
//
#include <hip/hip_runtime.h>
#include <math.h>

#define N_ATOMS 20000
#define M 12
#define B 41
#define ORIG 92
#define F 64
#define D 169        // 2F + B
#define NCONV 3
#define K 3
#define TWOK 6
#define H 128
#define N0 400
#define EPS 1e-5f
#define KB (K * B)   // 123

// MFMA geometry
#define KPAD 192                 // K dim padded to 6 steps of 32
#define NS 6                     // K-steps
#define ATOMS_PER_BLK 2
#define ROWS (ATOMS_PER_BLK * 16)  // 32
#define LFRAG 98304              // ushorts per (layer,img) fragment image: NS*32*64*8
#define WT_USHORTS (NCONV * 2 * LFRAG)

typedef __attribute__((ext_vector_type(8))) short bf16x8;
typedef __attribute__((ext_vector_type(4))) float f32x4;

// RNE f32 -> bf16 (bit trick), returns ushort pattern
__device__ inline unsigned short f32_to_bf16(float v) {
    unsigned int x = __float_as_uint(v);
    unsigned int r = (x + 0x7fffu + ((x >> 16) & 1u)) >> 16;
    return (unsigned short)r;
}
__device__ inline float bf16_to_f32(unsigned short u) {
    return __uint_as_float(((unsigned int)u) << 16);
}

// ---------------- embedding: x = atom_fea @ emb_w + emb_b ----------------
__global__ void emb_kernel(const float* __restrict__ atom_fea,
                           const float* __restrict__ emb_w,
                           const float* __restrict__ emb_b,
                           float* __restrict__ x) {
    int i = blockIdx.x * blockDim.x + threadIdx.x;
    if (i >= N_ATOMS * F) return;
    int n = i / F, f = i % F;
    const float* a = atom_fea + n * ORIG;
    float acc = emb_b[f];
    #pragma unroll 4
    for (int d = 0; d < ORIG; ++d)
        acc = fmaf(a[d], emb_w[d * F + f], acc);
    x[i] = acc;
}

// ------- prep: fc_w (NC,K,D,D) -> bf16 hi/lo B-fragment images ----------
// Padded col space (512): block b3 = col>>7:
//   b3<3 (gate k=b3): cc=col&127 -> source W col cc (filter 0-63, core 64-127)
//   b3==3 (bond): cc<123 -> k=cc/41, source col 128 + cc%41; else zero
// Fragment order: [layer][img][s][c16][lane][e] (ushort), where
//   col = c16*16 + (lane&15), k = s*32 + (lane>>4)*8 + e
__global__ void prep_kernel(const float* __restrict__ fc_w,
                            unsigned short* __restrict__ wt) {
    int i = blockIdx.x * blockDim.x + threadIdx.x;
    if (i >= NCONV * LFRAG) return;
    int layer = i / LFRAG;
    int r = i % LFRAG;
    int s = r / 16384;
    int r2 = r % 16384;
    int c16 = r2 / 512;
    int r3 = r2 % 512;
    int lane = r3 / 8;
    int e = r3 % 8;
    int col = c16 * 16 + (lane & 15);
    int k = s * 32 + (lane >> 4) * 8 + e;
    float v = 0.f;
    if (k < D) {
        int b3 = col >> 7, cc = col & 127;
        if (b3 < 3) {
            v = fc_w[((size_t)(layer * K + b3) * D + k) * D + cc];
        } else if (cc < KB) {
            int kk = cc / B, bb = cc - kk * B;
            v = fc_w[((size_t)(layer * K + kk) * D + k) * D + 2 * F + bb];
        }
    }
    unsigned short hi = f32_to_bf16(v);
    float hf = bf16_to_f32(hi);
    unsigned short lo = f32_to_bf16(v - hf);
    size_t off = (size_t)s * 16384 + c16 * 512 + lane * 8 + e;
    wt[(size_t)(layer * 2 + 0) * LFRAG + off] = hi;
    wt[(size_t)(layer * 2 + 1) * LFRAG + off] = lo;
}

// ---------------- MFMA conv: one block per 2 atoms ----------------
// A = [32 rows (2 atoms x 16, rows 12-15 pad=0)][192 k] bf16 hi/lo in LDS
//   (XOR swizzle: byte_in_row ^= (row&7)<<4)
// 4 waves; wave w owns col-tiles c16 = w*8 .. w*8+7 (128 cols).
//   w<3: gate block k=w (tiles 0-3 filter e, 4-7 core e)
//   w=3: bond block (cc = tt*16+lane15; k=cc/41, b=cc%41, cc<123)
// 3 split passes (hh, hl, lh) -- ll dropped (2^-18 relative).
// C layout per 16x16 tile: col=lane&15, row=(lane>>4)*4+reg  [verified]
template <bool NEED_NBR>
__global__ __launch_bounds__(256, 4)
void conv_mfma(const float* __restrict__ xin,
               const float* __restrict__ nbrin,
               const int* __restrict__ idx,
               const unsigned short* __restrict__ wtl,  // this layer's frags
               const float* __restrict__ fc_b,   // (K,D)
               const float* __restrict__ bn1_g,
               const float* __restrict__ bn1_b,
               const float* __restrict__ bn1_m,
               const float* __restrict__ bn1_v,  // (K,D)
               const float* __restrict__ bn2_g,
               const float* __restrict__ bn2_b,
               const float* __restrict__ bn2_m,
               const float* __restrict__ bn2_v,  // (K,F)
               const float* __restrict__ atom_w, // (K,2K)
               const float* __restrict__ atom_b, // (2K)
               const float* __restrict__ nbr_w,  // (K,2K)
               const float* __restrict__ nbr_b,  // (2K)
               float* __restrict__ xout,
               float* __restrict__ nbrout) {
    __shared__ unsigned short s_a[2 * ROWS * KPAD];        // 24576 B (hi, lo)
    __shared__ float s_sum[ATOMS_PER_BLK * K * F];         // 1536 B

    const int t = threadIdx.x;
    const int w = t >> 6;          // wave id
    const int l = t & 63;          // lane
    const int l15 = l & 15;
    const int lane3 = l >> 4;
    const int n0 = blockIdx.x * ATOMS_PER_BLK;

    // ---- stage A (bf16 hi/lo, swizzled): 6144 elems, 24 iters/thread ----
    for (int i = t; i < ROWS * KPAD; i += 256) {
        int row = i / KPAD;
        int k = i - row * KPAD;
        int a = row >> 4, m = row & 15;
        int n = n0 + a;
        float v = 0.f;
        if (m < M) {
            if (k < F)            v = xin[n * F + k];
            else if (k < 2 * F)   v = xin[idx[n * M + m] * F + (k - F)];
            else if (k < D)       v = nbrin[(n * M + m) * B + (k - 2 * F)];
        }
        unsigned short hi = f32_to_bf16(v);
        unsigned short lo = f32_to_bf16(v - bf16_to_f32(hi));
        int byte = row * (KPAD * 2) + ((k * 2) ^ ((row & 7) << 4));
        s_a[byte >> 1] = hi;
        s_a[(byte >> 1) + ROWS * KPAD] = lo;
    }
    __syncthreads();

    // ---- MFMA main loop: 3 split passes accumulated ----
    f32x4 acc[ATOMS_PER_BLK][8];
    #pragma unroll
    for (int a = 0; a < ATOMS_PER_BLK; ++a)
        #pragma unroll
        for (int tt = 0; tt < 8; ++tt)
            acc[a][tt] = (f32x4){0.f, 0.f, 0.f, 0.f};

    if (!(w == 3 && !NEED_NBR)) {
        for (int s = 0; s < NS; ++s) {
            bf16x8 ah[ATOMS_PER_BLK], al[ATOMS_PER_BLK];
            #pragma unroll
            for (int a = 0; a < ATOMS_PER_BLK; ++a) {
                int row = a * 16 + l15;
                int koff = s * 64 + lane3 * 16;                 // bytes
                int byte = row * (KPAD * 2) + (koff ^ ((row & 7) << 4));
                ah[a] = *reinterpret_cast<const bf16x8*>(&s_a[byte >> 1]);
                al[a] = *reinterpret_cast<const bf16x8*>(&s_a[(byte >> 1) + ROWS * KPAD]);
            }
            #pragma unroll
            for (int tt = 0; tt < 8; ++tt) {
                const unsigned short* wp =
                    wtl + (size_t)s * 16384 + (w * 8 + tt) * 512 + l * 8;
                bf16x8 bh = *reinterpret_cast<const bf16x8*>(wp);
                bf16x8 bl = *reinterpret_cast<const bf16x8*>(wp + LFRAG);
                #pragma unroll
                for (int a = 0; a < ATOMS_PER_BLK; ++a) {
                    acc[a][tt] = __builtin_amdgcn_mfma_f32_16x16x32_bf16(ah[a], bh, acc[a][tt], 0, 0, 0);
                    acc[a][tt] = __builtin_amdgcn_mfma_f32_16x16x32_bf16(ah[a], bl, acc[a][tt], 0, 0, 0);
                    acc[a][tt] = __builtin_amdgcn_mfma_f32_16x16x32_bf16(al[a], bh, acc[a][tt], 0, 0, 0);
                }
            }
        }
    }
    __syncthreads();   // all waves done reading s_a (bond wave will overlay it)

    float* s_nnk = reinterpret_cast<float*>(s_a);  // [2][3][12][41] f32 = 11808 B

    if (w < 3) {
        const int k = w;
        #pragma unroll
        for (int a = 0; a < ATOMS_PER_BLK; ++a) {
            #pragma unroll
            for (int tt = 0; tt < 4; ++tt) {
                int e = tt * 16 + l15;
                int cf = k * D + e, cr = cf + F, c2 = k * F + e;
                float sc_f = bn1_g[cf] * rsqrtf(bn1_v[cf] + EPS);
                float sh_f = bn1_b[cf] - bn1_m[cf] * sc_f;
                float bi_f = fc_b[cf];
                float sc_c = bn1_g[cr] * rsqrtf(bn1_v[cr] + EPS);
                float sh_c = bn1_b[cr] - bn1_m[cr] * sc_c;
                float bi_c = fc_b[cr];
                bool act = (lane3 < 3);   // rows 12-15 are pad
                float fv[4], cv[4];
                #pragma unroll
                for (int r = 0; r < 4; ++r) {
                    fv[r] = fmaf(acc[a][tt][r] + bi_f, sc_f, sh_f);
                    cv[r] = fmaxf(fmaf(acc[a][tt + 4][r] + bi_c, sc_c, sh_c), 0.f);
                }
                float mx = act ? fmaxf(fmaxf(fv[0], fv[1]), fmaxf(fv[2], fv[3])) : -1e30f;
                mx = fmaxf(mx, __shfl_xor(mx, 16));
                mx = fmaxf(mx, __shfl_xor(mx, 32));
                float se = 0.f, sp = 0.f;
                #pragma unroll
                for (int r = 0; r < 4; ++r) {
                    float ex = act ? __expf(fv[r] - mx) : 0.f;
                    se += ex;
                    sp = fmaf(ex, cv[r], sp);
                }
                se += __shfl_xor(se, 16);
                se += __shfl_xor(se, 32);
                sp += __shfl_xor(sp, 16);
                sp += __shfl_xor(sp, 32);
                float summed = sp / se;
                float sc2 = bn2_g[c2] * rsqrtf(bn2_v[c2] + EPS);
                float sh2 = bn2_b[c2] - bn2_m[c2] * sc2;
                float outv = xin[(n0 + a) * F + e] + fmaf(summed, sc2, sh2);
                if (lane3 == 0) s_sum[(a * K + k) * F + e] = outv;
            }
        }
    } else if (NEED_NBR) {
        #pragma unroll
        for (int a = 0; a < ATOMS_PER_BLK; ++a) {
            #pragma unroll
            for (int tt = 0; tt < 8; ++tt) {
                int cc = tt * 16 + l15;
                if (cc < KB) {
                    int kk = cc / B, bb = cc - kk * B;
                    int col = kk * D + 2 * F + bb;
                    float sc = bn1_g[col] * rsqrtf(bn1_v[col] + EPS);
                    float sh = bn1_b[col] - bn1_m[col] * sc;
                    float bi = fc_b[col];
                    #pragma unroll
                    for (int r = 0; r < 4; ++r) {
                        int m = lane3 * 4 + r;
                        if (m < M) {
                            float v = fmaf(acc[a][tt][r] + bi, sc, sh)
                                    + nbrin[((n0 + a) * M + m) * B + bb];
                            s_nnk[((a * K + kk) * M + m) * B + bb] = v;
                        }
                    }
                }
            }
        }
    }
    __syncthreads();

    // ---- atom gate: threads 0..127 = 2 atoms x 64 f ----
    if (t < ATOMS_PER_BLK * F) {
        int a2 = t >> 6, f = t & 63;
        float og[TWOK];
        #pragma unroll
        for (int j = 0; j < TWOK; ++j) {
            float v = atom_b[j];
            #pragma unroll
            for (int q = 0; q < K; ++q)
                v = fmaf(s_sum[(a2 * K + q) * F + f], atom_w[q * TWOK + j], v);
            og[j] = v;
        }
        float mx = fmaxf(fmaxf(og[K], og[K + 1]), og[K + 2]);
        float e0 = __expf(og[K] - mx), e1 = __expf(og[K + 1] - mx), e2 = __expf(og[K + 2] - mx);
        float inv = 1.f / (e0 + e1 + e2);
        xout[(n0 + a2) * F + f] = (og[0] * e0 + og[1] * e1 + og[2] * e2) * inv;
    }

    // ---- bond gate ----
    if (NEED_NBR) {
        for (int i = t; i < ATOMS_PER_BLK * M * B; i += 256) {
            int a2 = i / (M * B);
            int r = i - a2 * (M * B);
            int m = r / B, b = r - m * B;
            float ng[TWOK];
            #pragma unroll
            for (int j = 0; j < TWOK; ++j) {
                float v = nbr_b[j];
                #pragma unroll
                for (int q = 0; q < K; ++q)
                    v = fmaf(s_nnk[((a2 * K + q) * M + m) * B + b], nbr_w[q * TWOK + j], v);
                ng[j] = v;
            }
            float mx = fmaxf(fmaxf(ng[K], ng[K + 1]), ng[K + 2]);
            float e0 = __expf(ng[K] - mx), e1 = __expf(ng[K + 1] - mx), e2 = __expf(ng[K + 2] - mx);
            float inv = 1.f / (e0 + e1 + e2);
            nbrout[((n0 + a2) * M + m) * B + b] =
                (ng[0] * e0 + ng[1] * e1 + ng[2] * e2) * inv;
        }
    }
}

// ---------------- pooling: segment sums via atomics ----------------
__global__ void pool_kernel(const float* __restrict__ x,
                            const int* __restrict__ cidx,
                            float* __restrict__ sums,
                            float* __restrict__ cnt) {
    int i = blockIdx.x * blockDim.x + threadIdx.x;
    if (i >= N_ATOMS * F) return;
    int n = i / F, f = i % F;
    int c = cidx[n];
    atomicAdd(&sums[c * F + f], x[i]);
    if (f == 0) atomicAdd(&cnt[c], 1.0f);
}

// ---------------- head: mean -> relu -> fc1 -> relu -> out ----------------
__global__ void head_kernel(const float* __restrict__ sums,
                            const float* __restrict__ cnt,
                            const float* __restrict__ fc1_w,
                            const float* __restrict__ fc1_b,
                            const float* __restrict__ out_w,
                            const float* __restrict__ out_b,
                            float* __restrict__ out) {
    const int c = blockIdx.x;
    const int t = threadIdx.x;  // 128 threads
    __shared__ float a[F];
    __shared__ float red[H];
    float inv_cnt = 1.f / fmaxf(cnt[c], 1.0f);
    if (t < F) a[t] = fmaxf(sums[c * F + t] * inv_cnt, 0.f);
    __syncthreads();
    float hv = fc1_b[t];
    #pragma unroll 4
    for (int f = 0; f < F; ++f)
        hv = fmaf(a[f], fc1_w[f * H + t], hv);
    hv = fmaxf(hv, 0.f);
    red[t] = hv * out_w[t];
    __syncthreads();
    for (int s = H / 2; s > 0; s >>= 1) {
        if (t < s) red[t] += red[t + s];
        __syncthreads();
    }
    if (t == 0) out[c] = red[0] + out_b[0];
}

extern "C" void kernel_launch(void* const* d_in, const int* in_sizes, int n_in,
                              void* d_out, int out_size, void* d_ws, size_t ws_size,
                              hipStream_t stream) {
    (void)in_sizes; (void)n_in; (void)out_size; (void)ws_size;
    const float* atom_fea = (const float*)d_in[0];
    const float* nbr_fea  = (const float*)d_in[1];
    const int*   nbr_idx  = (const int*)d_in[2];
    const int*   cidx     = (const int*)d_in[3];
    // d_in[4] = n_crystals (fixed 400)
    const float* emb_w = (const float*)d_in[5];
    const float* emb_b = (const float*)d_in[6];
    const float* fc_w  = (const float*)d_in[7];
    const float* fc_b  = (const float*)d_in[8];
    const float* bn1_g = (const float*)d_in[9];
    const float* bn1_b = (const float*)d_in[10];
    const float* bn1_m = (const float*)d_in[11];
    const float* bn1_v = (const float*)d_in[12];
    const float* bn2_g = (const float*)d_in[13];
    const float* bn2_b = (const float*)d_in[14];
    const float* bn2_m = (const float*)d_in[15];
    const float* bn2_v = (const float*)d_in[16];
    const float* atom_w = (const float*)d_in[17];
    const float* atom_b = (const float*)d_in[18];
    const float* nbr_w  = (const float*)d_in[19];
    const float* nbr_b  = (const float*)d_in[20];
    const float* fc1_w  = (const float*)d_in[21];
    const float* fc1_b  = (const float*)d_in[22];
    const float* out_w  = (const float*)d_in[23];
    const float* out_b  = (const float*)d_in[24];
    float* out = (float*)d_out;

    float* xA   = (float*)d_ws;                    // N*F
    float* xB   = xA + (size_t)N_ATOMS * F;        // N*F
    float* nbrA = xB + (size_t)N_ATOMS * F;        // N*M*B
    float* nbrB = nbrA + (size_t)N_ATOMS * M * B;  // N*M*B
    float* sums = nbrB + (size_t)N_ATOMS * M * B;  // N0*F
    float* cnt  = sums + (size_t)N0 * F;           // N0
    unsigned short* wt = (unsigned short*)(cnt + N0);  // WT_USHORTS

    prep_kernel<<<(NCONV * LFRAG + 255) / 256, 256, 0, stream>>>(fc_w, wt);
    emb_kernel<<<(N_ATOMS * F + 255) / 256, 256, 0, stream>>>(atom_fea, emb_w, emb_b, xA);

    const int grid = N_ATOMS / ATOMS_PER_BLK;  // 10000

    // conv 0: xA -> xB, nbr_fea -> nbrA
    conv_mfma<true><<<grid, 256, 0, stream>>>(
        xA, nbr_fea, nbr_idx,
        wt, fc_b, bn1_g, bn1_b, bn1_m, bn1_v,
        bn2_g, bn2_b, bn2_m, bn2_v,
        atom_w, atom_b, nbr_w, nbr_b, xB, nbrA);
    // conv 1: xB -> xA, nbrA -> nbrB
    conv_mfma<true><<<grid, 256, 0, stream>>>(
        xB, nbrA, nbr_idx,
        wt + (size_t)2 * LFRAG, fc_b + (size_t)1 * K * D,
        bn1_g + (size_t)1 * K * D, bn1_b + (size_t)1 * K * D,
        bn1_m + (size_t)1 * K * D, bn1_v + (size_t)1 * K * D,
        bn2_g + (size_t)1 * K * F, bn2_b + (size_t)1 * K * F,
        bn2_m + (size_t)1 * K * F, bn2_v + (size_t)1 * K * F,
        atom_w + (size_t)1 * K * TWOK, atom_b + (size_t)1 * TWOK,
        nbr_w + (size_t)1 * K * TWOK, nbr_b + (size_t)1 * TWOK, xA, nbrB);
    // conv 2 (last): xA -> xB; new_nbr dead -> skip bond work entirely
    conv_mfma<false><<<grid, 256, 0, stream>>>(
        xA, nbrB, nbr_idx,
        wt + (size_t)4 * LFRAG, fc_b + (size_t)2 * K * D,
        bn1_g + (size_t)2 * K * D, bn1_b + (size_t)2 * K * D,
        bn1_m + (size_t)2 * K * D, bn1_v + (size_t)2 * K * D,
        bn2_g + (size_t)2 * K * F, bn2_b + (size_t)2 * K * F,
        bn2_m + (size_t)2 * K * F, bn2_v + (size_t)2 * K * F,
        atom_w + (size_t)2 * K * TWOK, atom_b + (size_t)2 * TWOK,
        nbr_w + (size_t)2 * K * TWOK, nbr_b + (size_t)2 * TWOK, xB, nbrA);

    hipMemsetAsync(sums, 0, (size_t)(N0 * F + N0) * sizeof(float), stream);
    pool_kernel<<<(N_ATOMS * F + 255) / 256, 256, 0, stream>>>(xB, cidx, sums, cnt);
    head_kernel<<<N0, H, 0, stream>>>(sums, cnt, fc1_w, fc1_b, out_w, out_b, out);
}

// Round 6
// 857.078 us; speedup vs baseline: 3.3434x; 1.1436x over previous
//
#include <hip/hip_runtime.h>
#include <math.h>

#define N_ATOMS 20000
#define M 12
#define B 41
#define ORIG 92
#define F 64
#define D 169        // 2F + B
#define NCONV 3
#define K 3
#define TWOK 6
#define H 128
#define N0 400
#define EPS 1e-5f
#define KB (K * B)   // 123

// MFMA geometry
#define KPAD 192                   // K dim padded to 6 steps of 32
#define NS 6                       // K-steps
#define ATOMS_PER_BLK 4
#define ROWS (ATOMS_PER_BLK * 16)  // 64
#define THREADS 512
#define LFRAG 98304                // ushorts per (layer,img) fragment image: NS*32*64*8
#define WT_USHORTS (NCONV * 2 * LFRAG)

typedef __attribute__((ext_vector_type(8))) short bf16x8;
typedef __attribute__((ext_vector_type(4))) float f32x4;

// RNE f32 -> bf16 (bit trick), returns ushort pattern
__device__ inline unsigned short f32_to_bf16(float v) {
    unsigned int x = __float_as_uint(v);
    unsigned int r = (x + 0x7fffu + ((x >> 16) & 1u)) >> 16;
    return (unsigned short)r;
}
__device__ inline float bf16_to_f32(unsigned short u) {
    return __uint_as_float(((unsigned int)u) << 16);
}

// ---------------- embedding: x = atom_fea @ emb_w + emb_b ----------------
__global__ void emb_kernel(const float* __restrict__ atom_fea,
                           const float* __restrict__ emb_w,
                           const float* __restrict__ emb_b,
                           float* __restrict__ x) {
    int i = blockIdx.x * blockDim.x + threadIdx.x;
    if (i >= N_ATOMS * F) return;
    int n = i / F, f = i % F;
    const float* a = atom_fea + n * ORIG;
    float acc = emb_b[f];
    #pragma unroll 4
    for (int d = 0; d < ORIG; ++d)
        acc = fmaf(a[d], emb_w[d * F + f], acc);
    x[i] = acc;
}

// ------- prep: fc_w (NC,K,D,D) -> bf16 hi/lo B-fragment images ----------
// Padded col space (512): block b3 = col>>7:
//   b3<3 (gate k=b3): cc=col&127 -> source W col cc (filter 0-63, core 64-127)
//   b3==3 (bond): cc<123 -> k=cc/41, source col 128 + cc%41; else zero
// Fragment order: [layer][img][s][c16][lane][e] (ushort), where
//   col = c16*16 + (lane&15), k = s*32 + (lane>>4)*8 + e
__global__ void prep_kernel(const float* __restrict__ fc_w,
                            unsigned short* __restrict__ wt) {
    int i = blockIdx.x * blockDim.x + threadIdx.x;
    if (i >= NCONV * LFRAG) return;
    int layer = i / LFRAG;
    int r = i % LFRAG;
    int s = r / 16384;
    int r2 = r % 16384;
    int c16 = r2 / 512;
    int r3 = r2 % 512;
    int lane = r3 / 8;
    int e = r3 % 8;
    int col = c16 * 16 + (lane & 15);
    int k = s * 32 + (lane >> 4) * 8 + e;
    float v = 0.f;
    if (k < D) {
        int b3 = col >> 7, cc = col & 127;
        if (b3 < 3) {
            v = fc_w[((size_t)(layer * K + b3) * D + k) * D + cc];
        } else if (cc < KB) {
            int kk = cc / B, bb = cc - kk * B;
            v = fc_w[((size_t)(layer * K + kk) * D + k) * D + 2 * F + bb];
        }
    }
    unsigned short hi = f32_to_bf16(v);
    float hf = bf16_to_f32(hi);
    unsigned short lo = f32_to_bf16(v - hf);
    size_t off = (size_t)s * 16384 + c16 * 512 + lane * 8 + e;
    wt[(size_t)(layer * 2 + 0) * LFRAG + off] = hi;
    wt[(size_t)(layer * 2 + 1) * LFRAG + off] = lo;
}

// ---------------- MFMA conv: one block per 4 atoms, 8 waves ----------------
// A = [64 rows (4 atoms x 16, rows 12-15 pad=0)][192 k] bf16 hi/lo in LDS
//   (XOR swizzle: byte_in_row ^= (row&7)<<4)
// 8 waves; each owns 4 c16-tiles (64 cols):
//   w<6 (gate, k=w>>1, half=w&1): tiles k*8+half*2+{0,1} (filter),
//                                 +4 (core) -> acc[a][j] / acc[a][j+2]
//   w>=6 (bond): tiles 24+(w-6)*4+{0..3}, cc=(w-6)*64+j*16+lane15
// 3 split passes (hh, hl, lh) -- ll dropped (2^-18 relative).
// C layout per 16x16 tile: col=lane&15, row=(lane>>4)*4+reg  [verified]
template <bool NEED_NBR>
__global__ __launch_bounds__(THREADS, 4)
void conv_mfma(const float* __restrict__ xin,
               const float* __restrict__ nbrin,
               const int* __restrict__ idx,
               const unsigned short* __restrict__ wtl,  // this layer's frags
               const float* __restrict__ fc_b,   // (K,D)
               const float* __restrict__ bn1_g,
               const float* __restrict__ bn1_b,
               const float* __restrict__ bn1_m,
               const float* __restrict__ bn1_v,  // (K,D)
               const float* __restrict__ bn2_g,
               const float* __restrict__ bn2_b,
               const float* __restrict__ bn2_m,
               const float* __restrict__ bn2_v,  // (K,F)
               const float* __restrict__ atom_w, // (K,2K)
               const float* __restrict__ atom_b, // (2K)
               const float* __restrict__ nbr_w,  // (K,2K)
               const float* __restrict__ nbr_b,  // (2K)
               float* __restrict__ xout,
               float* __restrict__ nbrout) {
    __shared__ unsigned short s_a[2 * ROWS * KPAD];        // 49152 B (hi, lo)
    __shared__ float s_sum[ATOMS_PER_BLK * K * F];         // 3072 B

    const int t = threadIdx.x;
    const int w = t >> 6;          // wave id 0..7
    const int l = t & 63;          // lane
    const int l15 = l & 15;
    const int lane3 = l >> 4;
    const int n0 = blockIdx.x * ATOMS_PER_BLK;

    // ---- stage A (bf16 hi/lo, swizzled): 12288 elems, 24 iters/thread ----
    for (int i = t; i < ROWS * KPAD; i += THREADS) {
        int row = i / KPAD;
        int k = i - row * KPAD;
        int a = row >> 4, m = row & 15;
        int n = n0 + a;
        float v = 0.f;
        if (m < M) {
            if (k < F)            v = xin[n * F + k];
            else if (k < 2 * F)   v = xin[idx[n * M + m] * F + (k - F)];
            else if (k < D)       v = nbrin[(n * M + m) * B + (k - 2 * F)];
        }
        unsigned short hi = f32_to_bf16(v);
        unsigned short lo = f32_to_bf16(v - bf16_to_f32(hi));
        int byte = row * (KPAD * 2) + ((k * 2) ^ ((row & 7) << 4));
        s_a[byte >> 1] = hi;
        s_a[(byte >> 1) + ROWS * KPAD] = lo;
    }
    __syncthreads();

    // ---- tile assignment: 4 c16 tiles per wave ----
    const int kk_gate = w >> 1, half = w & 1;
    int tile[4];
    if (w < 6) {
        tile[0] = kk_gate * 8 + half * 2 + 0;      // filter
        tile[1] = kk_gate * 8 + half * 2 + 1;      // filter
        tile[2] = tile[0] + 4;                     // core
        tile[3] = tile[1] + 4;                     // core
    } else {
        tile[0] = 24 + (w - 6) * 4 + 0;
        tile[1] = 24 + (w - 6) * 4 + 1;
        tile[2] = 24 + (w - 6) * 4 + 2;
        tile[3] = 24 + (w - 6) * 4 + 3;
    }

    // ---- MFMA main loop: 3 split passes accumulated ----
    f32x4 acc[ATOMS_PER_BLK][4];
    #pragma unroll
    for (int a = 0; a < ATOMS_PER_BLK; ++a)
        #pragma unroll
        for (int j = 0; j < 4; ++j)
            acc[a][j] = (f32x4){0.f, 0.f, 0.f, 0.f};

    if (!(w >= 6 && !NEED_NBR)) {
        for (int s = 0; s < NS; ++s) {
            bf16x8 ah[ATOMS_PER_BLK], al[ATOMS_PER_BLK];
            #pragma unroll
            for (int a = 0; a < ATOMS_PER_BLK; ++a) {
                int row = a * 16 + l15;
                int koff = s * 64 + lane3 * 16;                 // bytes
                int byte = row * (KPAD * 2) + (koff ^ ((row & 7) << 4));
                ah[a] = *reinterpret_cast<const bf16x8*>(&s_a[byte >> 1]);
                al[a] = *reinterpret_cast<const bf16x8*>(&s_a[(byte >> 1) + ROWS * KPAD]);
            }
            #pragma unroll
            for (int j = 0; j < 4; ++j) {
                const unsigned short* wp =
                    wtl + (size_t)s * 16384 + tile[j] * 512 + l * 8;
                bf16x8 bh = *reinterpret_cast<const bf16x8*>(wp);
                bf16x8 bl = *reinterpret_cast<const bf16x8*>(wp + LFRAG);
                #pragma unroll
                for (int a = 0; a < ATOMS_PER_BLK; ++a) {
                    acc[a][j] = __builtin_amdgcn_mfma_f32_16x16x32_bf16(ah[a], bh, acc[a][j], 0, 0, 0);
                    acc[a][j] = __builtin_amdgcn_mfma_f32_16x16x32_bf16(ah[a], bl, acc[a][j], 0, 0, 0);
                    acc[a][j] = __builtin_amdgcn_mfma_f32_16x16x32_bf16(al[a], bh, acc[a][j], 0, 0, 0);
                }
            }
        }
    }
    __syncthreads();   // all waves done reading s_a (bond waves will overlay it)

    float* s_nnk = reinterpret_cast<float*>(s_a);  // [4][3][12][41] f32 = 23616 B

    if (w < 6) {
        const int k = kk_gate;
        #pragma unroll
        for (int a = 0; a < ATOMS_PER_BLK; ++a) {
            #pragma unroll
            for (int j = 0; j < 2; ++j) {
                int e = (half * 2 + j) * 16 + l15;
                int cf = k * D + e, cr = cf + F, c2 = k * F + e;
                float sc_f = bn1_g[cf] * rsqrtf(bn1_v[cf] + EPS);
                float sh_f = bn1_b[cf] - bn1_m[cf] * sc_f;
                float bi_f = fc_b[cf];
                float sc_c = bn1_g[cr] * rsqrtf(bn1_v[cr] + EPS);
                float sh_c = bn1_b[cr] - bn1_m[cr] * sc_c;
                float bi_c = fc_b[cr];
                bool act = (lane3 < 3);   // rows 12-15 are pad
                float fv[4], cv[4];
                #pragma unroll
                for (int r = 0; r < 4; ++r) {
                    fv[r] = fmaf(acc[a][j][r] + bi_f, sc_f, sh_f);
                    cv[r] = fmaxf(fmaf(acc[a][j + 2][r] + bi_c, sc_c, sh_c), 0.f);
                }
                float mx = act ? fmaxf(fmaxf(fv[0], fv[1]), fmaxf(fv[2], fv[3])) : -1e30f;
                mx = fmaxf(mx, __shfl_xor(mx, 16));
                mx = fmaxf(mx, __shfl_xor(mx, 32));
                float se = 0.f, sp = 0.f;
                #pragma unroll
                for (int r = 0; r < 4; ++r) {
                    float ex = act ? __expf(fv[r] - mx) : 0.f;
                    se += ex;
                    sp = fmaf(ex, cv[r], sp);
                }
                se += __shfl_xor(se, 16);
                se += __shfl_xor(se, 32);
                sp += __shfl_xor(sp, 16);
                sp += __shfl_xor(sp, 32);
                float summed = sp / se;
                float sc2 = bn2_g[c2] * rsqrtf(bn2_v[c2] + EPS);
                float sh2 = bn2_b[c2] - bn2_m[c2] * sc2;
                float outv = xin[(n0 + a) * F + e] + fmaf(summed, sc2, sh2);
                if (lane3 == 0) s_sum[(a * K + k) * F + e] = outv;
            }
        }
    } else if (NEED_NBR) {
        #pragma unroll
        for (int a = 0; a < ATOMS_PER_BLK; ++a) {
            #pragma unroll
            for (int j = 0; j < 4; ++j) {
                int cc = (w - 6) * 64 + j * 16 + l15;
                if (cc < KB) {
                    int kk = cc / B, bb = cc - (cc / B) * B;
                    int col = kk * D + 2 * F + bb;
                    float sc = bn1_g[col] * rsqrtf(bn1_v[col] + EPS);
                    float sh = bn1_b[col] - bn1_m[col] * sc;
                    float bi = fc_b[col];
                    #pragma unroll
                    for (int r = 0; r < 4; ++r) {
                        int m = lane3 * 4 + r;
                        if (m < M) {
                            float v = fmaf(acc[a][j][r] + bi, sc, sh)
                                    + nbrin[((n0 + a) * M + m) * B + bb];
                            s_nnk[((a * K + kk) * M + m) * B + bb] = v;
                        }
                    }
                }
            }
        }
    }
    __syncthreads();

    // ---- atom gate: threads 0..255 = 4 atoms x 64 f ----
    if (t < ATOMS_PER_BLK * F) {
        int a2 = t >> 6, f = t & 63;
        float og[TWOK];
        #pragma unroll
        for (int j = 0; j < TWOK; ++j) {
            float v = atom_b[j];
            #pragma unroll
            for (int q = 0; q < K; ++q)
                v = fmaf(s_sum[(a2 * K + q) * F + f], atom_w[q * TWOK + j], v);
            og[j] = v;
        }
        float mx = fmaxf(fmaxf(og[K], og[K + 1]), og[K + 2]);
        float e0 = __expf(og[K] - mx), e1 = __expf(og[K + 1] - mx), e2 = __expf(og[K + 2] - mx);
        float inv = 1.f / (e0 + e1 + e2);
        xout[(n0 + a2) * F + f] = (og[0] * e0 + og[1] * e1 + og[2] * e2) * inv;
    }

    // ---- bond gate ----
    if (NEED_NBR) {
        for (int i = t; i < ATOMS_PER_BLK * M * B; i += THREADS) {
            int a2 = i / (M * B);
            int r = i - a2 * (M * B);
            int m = r / B, b = r - m * B;
            float ng[TWOK];
            #pragma unroll
            for (int j = 0; j < TWOK; ++j) {
                float v = nbr_b[j];
                #pragma unroll
                for (int q = 0; q < K; ++q)
                    v = fmaf(s_nnk[((a2 * K + q) * M + m) * B + b], nbr_w[q * TWOK + j], v);
                ng[j] = v;
            }
            float mx = fmaxf(fmaxf(ng[K], ng[K + 1]), ng[K + 2]);
            float e0 = __expf(ng[K] - mx), e1 = __expf(ng[K + 1] - mx), e2 = __expf(ng[K + 2] - mx);
            float inv = 1.f / (e0 + e1 + e2);
            nbrout[((n0 + a2) * M + m) * B + b] =
                (ng[0] * e0 + ng[1] * e1 + ng[2] * e2) * inv;
        }
    }
}

// ---------------- pooling: segment sums via atomics ----------------
__global__ void pool_kernel(const float* __restrict__ x,
                            const int* __restrict__ cidx,
                            float* __restrict__ sums,
                            float* __restrict__ cnt) {
    int i = blockIdx.x * blockDim.x + threadIdx.x;
    if (i >= N_ATOMS * F) return;
    int n = i / F, f = i % F;
    int c = cidx[n];
    atomicAdd(&sums[c * F + f], x[i]);
    if (f == 0) atomicAdd(&cnt[c], 1.0f);
}

// ---------------- head: mean -> relu -> fc1 -> relu -> out ----------------
__global__ void head_kernel(const float* __restrict__ sums,
                            const float* __restrict__ cnt,
                            const float* __restrict__ fc1_w,
                            const float* __restrict__ fc1_b,
                            const float* __restrict__ out_w,
                            const float* __restrict__ out_b,
                            float* __restrict__ out) {
    const int c = blockIdx.x;
    const int t = threadIdx.x;  // 128 threads
    __shared__ float a[F];
    __shared__ float red[H];
    float inv_cnt = 1.f / fmaxf(cnt[c], 1.0f);
    if (t < F) a[t] = fmaxf(sums[c * F + t] * inv_cnt, 0.f);
    __syncthreads();
    float hv = fc1_b[t];
    #pragma unroll 4
    for (int f = 0; f < F; ++f)
        hv = fmaf(a[f], fc1_w[f * H + t], hv);
    hv = fmaxf(hv, 0.f);
    red[t] = hv * out_w[t];
    __syncthreads();
    for (int s = H / 2; s > 0; s >>= 1) {
        if (t < s) red[t] += red[t + s];
        __syncthreads();
    }
    if (t == 0) out[c] = red[0] + out_b[0];
}

extern "C" void kernel_launch(void* const* d_in, const int* in_sizes, int n_in,
                              void* d_out, int out_size, void* d_ws, size_t ws_size,
                              hipStream_t stream) {
    (void)in_sizes; (void)n_in; (void)out_size; (void)ws_size;
    const float* atom_fea = (const float*)d_in[0];
    const float* nbr_fea  = (const float*)d_in[1];
    const int*   nbr_idx  = (const int*)d_in[2];
    const int*   cidx     = (const int*)d_in[3];
    // d_in[4] = n_crystals (fixed 400)
    const float* emb_w = (const float*)d_in[5];
    const float* emb_b = (const float*)d_in[6];
    const float* fc_w  = (const float*)d_in[7];
    const float* fc_b  = (const float*)d_in[8];
    const float* bn1_g = (const float*)d_in[9];
    const float* bn1_b = (const float*)d_in[10];
    const float* bn1_m = (const float*)d_in[11];
    const float* bn1_v = (const float*)d_in[12];
    const float* bn2_g = (const float*)d_in[13];
    const float* bn2_b = (const float*)d_in[14];
    const float* bn2_m = (const float*)d_in[15];
    const float* bn2_v = (const float*)d_in[16];
    const float* atom_w = (const float*)d_in[17];
    const float* atom_b = (const float*)d_in[18];
    const float* nbr_w  = (const float*)d_in[19];
    const float* nbr_b  = (const float*)d_in[20];
    const float* fc1_w  = (const float*)d_in[21];
    const float* fc1_b  = (const float*)d_in[22];
    const float* out_w  = (const float*)d_in[23];
    const float* out_b  = (const float*)d_in[24];
    float* out = (float*)d_out;

    float* xA   = (float*)d_ws;                    // N*F
    float* xB   = xA + (size_t)N_ATOMS * F;        // N*F
    float* nbrA = xB + (size_t)N_ATOMS * F;        // N*M*B
    float* nbrB = nbrA + (size_t)N_ATOMS * M * B;  // N*M*B
    float* sums = nbrB + (size_t)N_ATOMS * M * B;  // N0*F
    float* cnt  = sums + (size_t)N0 * F;           // N0
    unsigned short* wt = (unsigned short*)(cnt + N0);  // WT_USHORTS

    prep_kernel<<<(NCONV * LFRAG + 255) / 256, 256, 0, stream>>>(fc_w, wt);
    emb_kernel<<<(N_ATOMS * F + 255) / 256, 256, 0, stream>>>(atom_fea, emb_w, emb_b, xA);

    const int grid = N_ATOMS / ATOMS_PER_BLK;  // 5000

    // conv 0: xA -> xB, nbr_fea -> nbrA
    conv_mfma<true><<<grid, THREADS, 0, stream>>>(
        xA, nbr_fea, nbr_idx,
        wt, fc_b, bn1_g, bn1_b, bn1_m, bn1_v,
        bn2_g, bn2_b, bn2_m, bn2_v,
        atom_w, atom_b, nbr_w, nbr_b, xB, nbrA);
    // conv 1: xB -> xA, nbrA -> nbrB
    conv_mfma<true><<<grid, THREADS, 0, stream>>>(
        xB, nbrA, nbr_idx,
        wt + (size_t)2 * LFRAG, fc_b + (size_t)1 * K * D,
        bn1_g + (size_t)1 * K * D, bn1_b + (size_t)1 * K * D,
        bn1_m + (size_t)1 * K * D, bn1_v + (size_t)1 * K * D,
        bn2_g + (size_t)1 * K * F, bn2_b + (size_t)1 * K * F,
        bn2_m + (size_t)1 * K * F, bn2_v + (size_t)1 * K * F,
        atom_w + (size_t)1 * K * TWOK, atom_b + (size_t)1 * TWOK,
        nbr_w + (size_t)1 * K * TWOK, nbr_b + (size_t)1 * TWOK, xA, nbrB);
    // conv 2 (last): xA -> xB; new_nbr dead -> skip bond work entirely
    conv_mfma<false><<<grid, THREADS, 0, stream>>>(
        xA, nbrB, nbr_idx,
        wt + (size_t)4 * LFRAG, fc_b + (size_t)2 * K * D,
        bn1_g + (size_t)2 * K * D, bn1_b + (size_t)2 * K * D,
        bn1_m + (size_t)2 * K * D, bn1_v + (size_t)2 * K * D,
        bn2_g + (size_t)2 * K * F, bn2_b + (size_t)2 * K * F,
        bn2_m + (size_t)2 * K * F, bn2_v + (size_t)2 * K * F,
        atom_w + (size_t)2 * K * TWOK, atom_b + (size_t)2 * TWOK,
        nbr_w + (size_t)2 * K * TWOK, nbr_b + (size_t)2 * TWOK, xB, nbrA);

    hipMemsetAsync(sums, 0, (size_t)(N0 * F + N0) * sizeof(float), stream);
    pool_kernel<<<(N_ATOMS * F + 255) / 256, 256, 0, stream>>>(xB, cidx, sums, cnt);
    head_kernel<<<N0, H, 0, stream>>>(sums, cnt, fc1_w, fc1_b, out_w, out_b, out);
}